// Round 4
// baseline (574.814 us; speedup 1.0000x reference)
//
#include <hip/hip_runtime.h>
#include <math.h>

#define N_POS 8192
#define BATCH 4
#define N_GT 512
#define BG 2048
#define EPSV 1e-6f

#define KA_BLOCKS 2048
#define ROWS_A 4
#define KC_BLOCKS 2048
#define ROWS_C 4

// workspace float offsets
// dpack layout: dpack[n][j], j = 8*t + k  (column j's batch = j>>9 = wave id of owner thread)
#define WS_DPACK 0                           // [8192][2048] = 64 MiB
#define WS_PARTS (N_POS * BG)                // [2048][2048] kC partials = 16 MiB
#define WS_MIND  (WS_PARTS + KC_BLOCKS * BG) // [4][8192] min_g D
#define WS_MAXP  (WS_MIND + BATCH * N_POS)   // [2048] kA block maxes
#define WS_SC    (WS_MAXP + KA_BLOCKS)       // [0]=maxd [1]=pmin [2]=prange [3..6]=n_est [7..10]=t1 [11]=t2sum

// ---------------- kA: single pass over dis_matrix ----------------
// global max partials; gather gt columns -> dpack (float4-coalesced); per-(b,n) min -> minD
__global__ __launch_bounds__(256) void whd_kA(const float* __restrict__ dis,
                                              const int* __restrict__ gt,
                                              float* __restrict__ wsf) {
    __shared__ float rowbuf[N_POS];     // 32 KB
    __shared__ unsigned short gtl[BG];  // 4 KB
    __shared__ float smax[4];
    const int t = threadIdx.x;
    const int wv = t >> 6, lane = t & 63;
    const int row0 = blockIdx.x * ROWS_A;
    float* dpack = wsf + WS_DPACK;
    float* minD = wsf + WS_MIND;

    for (int i = t; i < BG; i += 256) gtl[i] = (unsigned short)gt[i];
    __syncthreads();
    // thread t owns packed columns j = 8t..8t+7; all 8 belong to batch (8t+k)>>9 == wv
    int c[8];
    #pragma unroll
    for (int k = 0; k < 8; k++) c[k] = gtl[8 * t + k];

    float tmax = -INFINITY;
    for (int r = 0; r < ROWS_A; r++) {
        const int n = row0 + r;
        if (r > 0) __syncthreads();     // previous row's gathers complete before overwrite
        const float4* src = (const float4*)(dis + (size_t)n * N_POS);
        float4* dstl = (float4*)rowbuf;
        #pragma unroll
        for (int j = 0; j < N_POS / 4 / 256; j++) {
            int i = t + 256 * j;
            float4 v = src[i];
            tmax = fmaxf(tmax, fmaxf(fmaxf(v.x, v.y), fmaxf(v.z, v.w)));
            dstl[i] = v;
        }
        __syncthreads();
        float g0 = rowbuf[c[0]], g1 = rowbuf[c[1]], g2 = rowbuf[c[2]], g3 = rowbuf[c[3]];
        float g4 = rowbuf[c[4]], g5 = rowbuf[c[5]], g6 = rowbuf[c[6]], g7 = rowbuf[c[7]];
        float4* dst = (float4*)(dpack + (size_t)n * BG + 8 * t);
        dst[0] = make_float4(g0, g1, g2, g3);
        dst[1] = make_float4(g4, g5, g6, g7);
        // per-wave (= per-batch) min over this wave's 512 columns
        float m = fminf(fminf(fminf(g0, g1), fminf(g2, g3)),
                        fminf(fminf(g4, g5), fminf(g6, g7)));
        #pragma unroll
        for (int off = 32; off; off >>= 1) m = fminf(m, __shfl_xor(m, off, 64));
        if (lane == 0) minD[wv * N_POS + n] = m;
    }
    // block max partial
    #pragma unroll
    for (int off = 32; off; off >>= 1) tmax = fmaxf(tmax, __shfl_down(tmax, off, 64));
    if (lane == 0) smax[wv] = tmax;
    __syncthreads();
    if (t == 0)
        wsf[WS_MAXP + blockIdx.x] = fmaxf(fmaxf(smax[0], smax[1]), fmaxf(smax[2], smax[3]));
}

// ---------------- kB: finalize scalars + n_est/term1 (single block) ----------------
__global__ __launch_bounds__(1024) void whd_kB(const float* __restrict__ prob,
                                               float* __restrict__ wsf) {
    __shared__ float red[1024];
    const int t = threadIdx.x;
    float m = -INFINITY;
    for (int i = t; i < KA_BLOCKS; i += 1024) m = fmaxf(m, wsf[WS_MAXP + i]);
    red[t] = m; __syncthreads();
    for (int s = 512; s; s >>= 1) { if (t < s) red[t] = fmaxf(red[t], red[t + s]); __syncthreads(); }
    float maxdist = red[0]; __syncthreads();
    float lmin = INFINITY, lmax = -INFINITY;
    for (int i = t; i < BATCH * N_POS; i += 1024) {
        float v = prob[i];
        lmin = fminf(lmin, v); lmax = fmaxf(lmax, v);
    }
    red[t] = lmin; __syncthreads();
    for (int s = 512; s; s >>= 1) { if (t < s) red[t] = fminf(red[t], red[t + s]); __syncthreads(); }
    float pmin = red[0]; __syncthreads();
    red[t] = lmax; __syncthreads();
    for (int s = 512; s; s >>= 1) { if (t < s) red[t] = fmaxf(red[t], red[t + s]); __syncthreads(); }
    float pmax = red[0]; __syncthreads();
    float invr = 1.0f / (pmax - pmin);
    const float* minD = wsf + WS_MIND;
    for (int b = 0; b < BATCH; b++) {
        float sp = 0.f, spm = 0.f;
        for (int i = t; i < N_POS; i += 1024) {
            float p = (prob[b * N_POS + i] - pmin) * invr;
            p = fminf(fmaxf(p, 0.f), 1.f);
            sp += p;
            spm += p * minD[b * N_POS + i];
        }
        red[t] = sp; __syncthreads();
        for (int s = 512; s; s >>= 1) { if (t < s) red[t] += red[t + s]; __syncthreads(); }
        if (t == 0) wsf[WS_SC + 3 + b] = red[0];
        __syncthreads();
        red[t] = spm; __syncthreads();
        for (int s = 512; s; s >>= 1) { if (t < s) red[t] += red[t + s]; __syncthreads(); }
        if (t == 0) wsf[WS_SC + 7 + b] = red[0];
        __syncthreads();
    }
    if (t == 0) {
        wsf[WS_SC + 0] = maxdist;
        wsf[WS_SC + 1] = pmin;
        wsf[WS_SC + 2] = pmax - pmin;
        wsf[WS_SC + 11] = 0.f;  // t2 accumulator (ws is poisoned 0xAA)
    }
}

// ---------------- kC: reciprocal pass over packed columns ----------------
__global__ __launch_bounds__(256) void whd_kC(const float* __restrict__ prob,
                                              float* __restrict__ wsf) {
    const int t = threadIdx.x;
    const int wv = t >> 6;              // = batch of all 8 owned columns
    const int row0 = blockIdx.x * ROWS_C;
    const float* dpack = wsf + WS_DPACK;
    const float maxd = wsf[WS_SC + 0];
    const float pmin = wsf[WS_SC + 1];
    const float invr = 1.0f / wsf[WS_SC + 2];
    float acc[8];
    #pragma unroll
    for (int k = 0; k < 8; k++) acc[k] = 0.f;
    #pragma unroll
    for (int r = 0; r < ROWS_C; r++) {
        const int n = row0 + r;
        float p = (prob[wv * N_POS + n] - pmin) * invr;
        p = fminf(fmaxf(p, 0.f), 1.f);
        const float4* rp = (const float4*)(dpack + (size_t)n * BG + 8 * t);
        float4 v0 = rp[0], v1 = rp[1];
        acc[0] += 1.0f / (fmaf(p, v0.x - maxd, maxd) + EPSV);
        acc[1] += 1.0f / (fmaf(p, v0.y - maxd, maxd) + EPSV);
        acc[2] += 1.0f / (fmaf(p, v0.z - maxd, maxd) + EPSV);
        acc[3] += 1.0f / (fmaf(p, v0.w - maxd, maxd) + EPSV);
        acc[4] += 1.0f / (fmaf(p, v1.x - maxd, maxd) + EPSV);
        acc[5] += 1.0f / (fmaf(p, v1.y - maxd, maxd) + EPSV);
        acc[6] += 1.0f / (fmaf(p, v1.z - maxd, maxd) + EPSV);
        acc[7] += 1.0f / (fmaf(p, v1.w - maxd, maxd) + EPSV);
    }
    float4* op = (float4*)(wsf + WS_PARTS + (size_t)blockIdx.x * BG + 8 * t);
    op[0] = make_float4(acc[0], acc[1], acc[2], acc[3]);
    op[1] = make_float4(acc[4], acc[5], acc[6], acc[7]);
}

// ---------------- kD: reduce partials over chunks -> term2 sum ----------------
__global__ __launch_bounds__(256) void whd_kD(float* __restrict__ wsf) {
    __shared__ float red[256];
    const int t = threadIdx.x;
    const int col = blockIdx.x * 256 + t;
    const float* parts = wsf + WS_PARTS;
    float s = 0.f;
    #pragma unroll 8
    for (int ch = 0; ch < KC_BLOCKS; ch++) s += parts[(size_t)ch * BG + col];
    float val = (float)N_POS / s;       // (mean_n 1/(w+eps))^-1
    red[t] = val; __syncthreads();
    for (int st = 128; st; st >>= 1) { if (t < st) red[t] += red[t + st]; __syncthreads(); }
    if (t == 0) atomicAdd(&wsf[WS_SC + 11], red[0]);
}

// ---------------- kE: final scalar ----------------
__global__ __launch_bounds__(64) void whd_kE(const float* __restrict__ wsf,
                                             float* __restrict__ out) {
    if (threadIdx.x == 0) {
        float term1 = 0.f;
        for (int b = 0; b < BATCH; b++)
            term1 += wsf[WS_SC + 7 + b] / (wsf[WS_SC + 3 + b] + EPSV);
        term1 *= (1.0f / BATCH);
        float term2 = wsf[WS_SC + 11] * (1.0f / BG);
        out[0] = term1 + term2;
    }
}

extern "C" void kernel_launch(void* const* d_in, const int* in_sizes, int n_in,
                              void* d_out, int out_size, void* d_ws, size_t ws_size,
                              hipStream_t stream) {
    const float* prob = (const float*)d_in[0];   // (4, 8192) fp32
    const int* gt = (const int*)d_in[1];         // (4, 512) int32
    const float* dis = (const float*)d_in[2];    // (8192, 8192) fp32
    float* out = (float*)d_out;
    float* wsf = (float*)d_ws;

    whd_kA<<<KA_BLOCKS, 256, 0, stream>>>(dis, gt, wsf);
    whd_kB<<<1, 1024, 0, stream>>>(prob, wsf);
    whd_kC<<<KC_BLOCKS, 256, 0, stream>>>(prob, wsf);
    whd_kD<<<BG / 256, 256, 0, stream>>>(wsf);
    whd_kE<<<1, 64, 0, stream>>>(wsf, out);
}

// Round 5
// 432.327 us; speedup vs baseline: 1.3296x; 1.3296x over previous
//
#include <hip/hip_runtime.h>
#include <math.h>

#define N_POS 8192
#define BATCH 4
#define N_GT 512
#define BG 2048
#define EPSV 1e-6f

#define KA_BLOCKS 2048
#define ROWS_A 4
#define KC_BLOCKS 1024
#define ROWS_C 8
#define RG 32                                // kD1 row-groups
#define CHUNKS_PER_RG (KC_BLOCKS / RG)       // 32

// workspace float offsets
// dpack layout: dpack[n][j], j = 8*t + k  (column j's batch = j>>9 = wave id of owner)
#define WS_DPACK 0                              // [8192][2048] = 64 MiB
#define WS_PARTS (N_POS * BG)                   // [1024][2048] = 8 MiB
#define WS_PARTS2 (WS_PARTS + KC_BLOCKS * BG)   // [32][2048] = 256 KiB
#define WS_MIND  (WS_PARTS2 + RG * BG)          // [4][8192] min_g D
#define WS_MAXP  (WS_MIND + BATCH * N_POS)      // [2048] kA block maxes
#define WS_SC    (WS_MAXP + KA_BLOCKS)          // [0]=maxd [1]=pmin [2]=prange [3..6]=n_est [7..10]=t1 [11]=t2sum

// ---------------- kA: single pass over dis_matrix ----------------
__global__ __launch_bounds__(256) void whd_kA(const float* __restrict__ dis,
                                              const int* __restrict__ gt,
                                              float* __restrict__ wsf) {
    __shared__ float rowbuf[N_POS];     // 32 KB
    __shared__ unsigned short gtl[BG];  // 4 KB
    __shared__ float smax[4];
    const int t = threadIdx.x;
    const int wv = t >> 6, lane = t & 63;
    const int row0 = blockIdx.x * ROWS_A;
    float* dpack = wsf + WS_DPACK;
    float* minD = wsf + WS_MIND;

    for (int i = t; i < BG; i += 256) gtl[i] = (unsigned short)gt[i];
    __syncthreads();
    int c[8];
    #pragma unroll
    for (int k = 0; k < 8; k++) c[k] = gtl[8 * t + k];

    float tmax = -INFINITY;
    for (int r = 0; r < ROWS_A; r++) {
        const int n = row0 + r;
        if (r > 0) __syncthreads();
        const float4* src = (const float4*)(dis + (size_t)n * N_POS);
        float4* dstl = (float4*)rowbuf;
        #pragma unroll
        for (int j = 0; j < N_POS / 4 / 256; j++) {
            int i = t + 256 * j;
            float4 v = src[i];
            tmax = fmaxf(tmax, fmaxf(fmaxf(v.x, v.y), fmaxf(v.z, v.w)));
            dstl[i] = v;
        }
        __syncthreads();
        float g0 = rowbuf[c[0]], g1 = rowbuf[c[1]], g2 = rowbuf[c[2]], g3 = rowbuf[c[3]];
        float g4 = rowbuf[c[4]], g5 = rowbuf[c[5]], g6 = rowbuf[c[6]], g7 = rowbuf[c[7]];
        float4* dst = (float4*)(dpack + (size_t)n * BG + 8 * t);
        dst[0] = make_float4(g0, g1, g2, g3);
        dst[1] = make_float4(g4, g5, g6, g7);
        float m = fminf(fminf(fminf(g0, g1), fminf(g2, g3)),
                        fminf(fminf(g4, g5), fminf(g6, g7)));
        #pragma unroll
        for (int off = 32; off; off >>= 1) m = fminf(m, __shfl_xor(m, off, 64));
        if (lane == 0) minD[wv * N_POS + n] = m;
    }
    #pragma unroll
    for (int off = 32; off; off >>= 1) tmax = fmaxf(tmax, __shfl_down(tmax, off, 64));
    if (lane == 0) smax[wv] = tmax;
    __syncthreads();
    if (t == 0)
        wsf[WS_MAXP + blockIdx.x] = fmaxf(fmaxf(smax[0], smax[1]), fmaxf(smax[2], smax[3]));
}

// ---------------- kB: finalize scalars + n_est/term1 (single block) ----------------
__global__ __launch_bounds__(1024) void whd_kB(const float* __restrict__ prob,
                                               float* __restrict__ wsf) {
    __shared__ float red[1024];
    const int t = threadIdx.x;
    float m = -INFINITY;
    for (int i = t; i < KA_BLOCKS; i += 1024) m = fmaxf(m, wsf[WS_MAXP + i]);
    red[t] = m; __syncthreads();
    for (int s = 512; s; s >>= 1) { if (t < s) red[t] = fmaxf(red[t], red[t + s]); __syncthreads(); }
    float maxdist = red[0]; __syncthreads();
    float lmin = INFINITY, lmax = -INFINITY;
    for (int i = t; i < BATCH * N_POS; i += 1024) {
        float v = prob[i];
        lmin = fminf(lmin, v); lmax = fmaxf(lmax, v);
    }
    red[t] = lmin; __syncthreads();
    for (int s = 512; s; s >>= 1) { if (t < s) red[t] = fminf(red[t], red[t + s]); __syncthreads(); }
    float pmin = red[0]; __syncthreads();
    red[t] = lmax; __syncthreads();
    for (int s = 512; s; s >>= 1) { if (t < s) red[t] = fmaxf(red[t], red[t + s]); __syncthreads(); }
    float pmax = red[0]; __syncthreads();
    float invr = 1.0f / (pmax - pmin);
    const float* minD = wsf + WS_MIND;
    for (int b = 0; b < BATCH; b++) {
        float sp = 0.f, spm = 0.f;
        for (int i = t; i < N_POS; i += 1024) {
            float p = (prob[b * N_POS + i] - pmin) * invr;
            p = fminf(fmaxf(p, 0.f), 1.f);
            sp += p;
            spm += p * minD[b * N_POS + i];
        }
        red[t] = sp; __syncthreads();
        for (int s = 512; s; s >>= 1) { if (t < s) red[t] += red[t + s]; __syncthreads(); }
        if (t == 0) wsf[WS_SC + 3 + b] = red[0];
        __syncthreads();
        red[t] = spm; __syncthreads();
        for (int s = 512; s; s >>= 1) { if (t < s) red[t] += red[t + s]; __syncthreads(); }
        if (t == 0) wsf[WS_SC + 7 + b] = red[0];
        __syncthreads();
    }
    if (t == 0) {
        wsf[WS_SC + 0] = maxdist;
        wsf[WS_SC + 1] = pmin;
        wsf[WS_SC + 2] = pmax - pmin;
        wsf[WS_SC + 11] = 0.f;  // t2 accumulator (ws is poisoned 0xAA)
    }
}

// ---------------- kC: reciprocal pass over packed columns ----------------
__global__ __launch_bounds__(256) void whd_kC(const float* __restrict__ prob,
                                              float* __restrict__ wsf) {
    const int t = threadIdx.x;
    const int wv = t >> 6;              // batch of all 8 owned columns
    const int row0 = blockIdx.x * ROWS_C;
    const float* dpack = wsf + WS_DPACK;
    const float maxd = wsf[WS_SC + 0];
    const float pmin = wsf[WS_SC + 1];
    const float invr = 1.0f / wsf[WS_SC + 2];
    float acc[8];
    #pragma unroll
    for (int k = 0; k < 8; k++) acc[k] = 0.f;
    #pragma unroll
    for (int r = 0; r < ROWS_C; r++) {
        const int n = row0 + r;
        float p = (prob[wv * N_POS + n] - pmin) * invr;
        p = fminf(fmaxf(p, 0.f), 1.f);
        const float4* rp = (const float4*)(dpack + (size_t)n * BG + 8 * t);
        float4 v0 = rp[0], v1 = rp[1];
        acc[0] += 1.0f / (fmaf(p, v0.x - maxd, maxd) + EPSV);
        acc[1] += 1.0f / (fmaf(p, v0.y - maxd, maxd) + EPSV);
        acc[2] += 1.0f / (fmaf(p, v0.z - maxd, maxd) + EPSV);
        acc[3] += 1.0f / (fmaf(p, v0.w - maxd, maxd) + EPSV);
        acc[4] += 1.0f / (fmaf(p, v1.x - maxd, maxd) + EPSV);
        acc[5] += 1.0f / (fmaf(p, v1.y - maxd, maxd) + EPSV);
        acc[6] += 1.0f / (fmaf(p, v1.z - maxd, maxd) + EPSV);
        acc[7] += 1.0f / (fmaf(p, v1.w - maxd, maxd) + EPSV);
    }
    float4* op = (float4*)(wsf + WS_PARTS + (size_t)blockIdx.x * BG + 8 * t);
    op[0] = make_float4(acc[0], acc[1], acc[2], acc[3]);
    op[1] = make_float4(acc[4], acc[5], acc[6], acc[7]);
}

// ---------------- kD1: coalesced partial-sum tree, stage 1 ----------------
// grid (8 col-tiles, 32 row-groups); each block sums 32 chunks for 256 contiguous cols
__global__ __launch_bounds__(256) void whd_kD1(float* __restrict__ wsf) {
    const int t = threadIdx.x;
    const int col = blockIdx.x * 256 + t;
    const int rg = blockIdx.y;
    const float* parts = wsf + WS_PARTS + (size_t)rg * CHUNKS_PER_RG * BG;
    float s = 0.f;
    #pragma unroll 8
    for (int ch = 0; ch < CHUNKS_PER_RG; ch++) s += parts[(size_t)ch * BG + col];
    wsf[WS_PARTS2 + (size_t)rg * BG + col] = s;
}

// ---------------- kD2: finish column sums -> term2 sum ----------------
__global__ __launch_bounds__(256) void whd_kD2(float* __restrict__ wsf) {
    __shared__ float red[256];
    const int t = threadIdx.x;
    const int col = blockIdx.x * 256 + t;
    const float* p2 = wsf + WS_PARTS2;
    float s = 0.f;
    #pragma unroll
    for (int rg = 0; rg < RG; rg++) s += p2[(size_t)rg * BG + col];
    float val = (float)N_POS / s;       // (mean_n 1/(w+eps))^-1
    red[t] = val; __syncthreads();
    for (int st = 128; st; st >>= 1) { if (t < st) red[t] += red[t + st]; __syncthreads(); }
    if (t == 0) atomicAdd(&wsf[WS_SC + 11], red[0]);
}

// ---------------- kE: final scalar ----------------
__global__ __launch_bounds__(64) void whd_kE(const float* __restrict__ wsf,
                                             float* __restrict__ out) {
    if (threadIdx.x == 0) {
        float term1 = 0.f;
        for (int b = 0; b < BATCH; b++)
            term1 += wsf[WS_SC + 7 + b] / (wsf[WS_SC + 3 + b] + EPSV);
        term1 *= (1.0f / BATCH);
        float term2 = wsf[WS_SC + 11] * (1.0f / BG);
        out[0] = term1 + term2;
    }
}

extern "C" void kernel_launch(void* const* d_in, const int* in_sizes, int n_in,
                              void* d_out, int out_size, void* d_ws, size_t ws_size,
                              hipStream_t stream) {
    const float* prob = (const float*)d_in[0];   // (4, 8192) fp32
    const int* gt = (const int*)d_in[1];         // (4, 512) int32
    const float* dis = (const float*)d_in[2];    // (8192, 8192) fp32
    float* out = (float*)d_out;
    float* wsf = (float*)d_ws;

    whd_kA<<<KA_BLOCKS, 256, 0, stream>>>(dis, gt, wsf);
    whd_kB<<<1, 1024, 0, stream>>>(prob, wsf);
    whd_kC<<<KC_BLOCKS, 256, 0, stream>>>(prob, wsf);
    whd_kD1<<<dim3(BG / 256, RG), 256, 0, stream>>>(wsf);
    whd_kD2<<<BG / 256, 256, 0, stream>>>(wsf);
    whd_kE<<<1, 64, 0, stream>>>(wsf, out);
}